// Round 2
// baseline (238.531 us; speedup 1.0000x reference)
//
#include <hip/hip_runtime.h>

#define N_TOK 4096
#define DIM   1024

typedef __bf16 bf16x8 __attribute__((ext_vector_type(8)));
typedef float  f32x4  __attribute__((ext_vector_type(4)));

__device__ __forceinline__ unsigned short f2bf(float f) {
  union { float f; unsigned u; } v; v.f = f;
  unsigned u = v.u;
  return (unsigned short)((u + 0x7fffu + ((u >> 16) & 1u)) >> 16);
}
__device__ __forceinline__ float bf2f(unsigned short h) {
  union { unsigned u; float f; } v; v.u = ((unsigned)h) << 16;
  return v.f;
}

// async global->LDS, 16 B/lane: lane's data lands at (uniform lds base) + lane*16
__device__ __forceinline__ void gll16(const unsigned short* g,
                                      unsigned short* l) {
  __builtin_amdgcn_global_load_lds(
      (const __attribute__((address_space(1))) unsigned int*)g,
      (__attribute__((address_space(3))) unsigned int*)l, 16, 0, 0);
}

// ---------------------------------------------------------------------------
// Fused prep kernel — all independent pre-GEMM work in ONE launch:
//   job CVT  [0,2048):     xb = bf16(x), 8 elems/thread
//   job TQ/TK/TV (+1024):  Wt[n][k] = bf16(W[k][n]) via 32x32 LDS tile
//   job ZERO [5120,5888):  out rows 1024..4096 = 0  (exact 3M floats)
//   job LSUM [5888,5892):  Lsum = 0
//   job BIAS [5892,5895):  ball = {bq/32, bk, bv}
// ---------------------------------------------------------------------------
#define PB_CVT 0
#define PB_TQ 2048
#define PB_ZERO 5120
#define PB_LSUM 5888
#define PB_BIAS 5892
#define PB_TOTAL 5895

__global__ void prep(const float* __restrict__ x, const float* __restrict__ Wq,
                     const float* __restrict__ Wk, const float* __restrict__ Wv,
                     const float* __restrict__ bq, const float* __restrict__ bk,
                     const float* __restrict__ bv,
                     unsigned short* __restrict__ xb,
                     unsigned short* __restrict__ Wt,
                     float* __restrict__ out, float* __restrict__ ball,
                     float* __restrict__ Lsum) {
  const int b = blockIdx.x;
  const int t = threadIdx.x;
  if (b < PB_TQ) {  // CVT
    const int i = ((b - PB_CVT) * 256 + t) * 8;
    float4 v0 = *(const float4*)(x + i);
    float4 v1 = *(const float4*)(x + i + 4);
    ushort4 r0, r1;
    r0.x = f2bf(v0.x); r0.y = f2bf(v0.y); r0.z = f2bf(v0.z); r0.w = f2bf(v0.w);
    r1.x = f2bf(v1.x); r1.y = f2bf(v1.y); r1.z = f2bf(v1.z); r1.w = f2bf(v1.w);
    *(ushort4*)(xb + i) = r0;
    *(ushort4*)(xb + i + 4) = r1;
  } else if (b < PB_ZERO) {  // transpose one 32x32 tile of one W
    const int which = (b - PB_TQ) >> 10;          // 0,1,2
    const int lb = (b - PB_TQ) & 1023;
    const float* W = (which == 0) ? Wq : (which == 1) ? Wk : Wv;
    unsigned short* D = Wt + (size_t)which * 1024 * 1024;
    __shared__ float tile[32][33];
    const int bx = (lb & 31) * 32, by = (lb >> 5) * 32;
    const int tx = t & 31, ty = t >> 5;  // ty in 0..7
    for (int r = ty; r < 32; r += 8)
      tile[r][tx] = W[(size_t)(by + r) * DIM + bx + tx];
    __syncthreads();
    for (int r = ty; r < 32; r += 8)
      D[(size_t)(bx + r) * DIM + by + tx] = f2bf(tile[tx][r]);
  } else if (b < PB_LSUM) {  // zero out rows >= 1024 (3M floats)
    float4* p = (float4*)(out + (size_t)1024 * DIM);
    const int i = ((b - PB_ZERO) * 256 + t) * 4;
#pragma unroll
    for (int c = 0; c < 4; c++) p[i + c] = make_float4(0.f, 0.f, 0.f, 0.f);
  } else if (b < PB_BIAS) {  // Lsum zero
    const int i = ((b - PB_LSUM) * 256 + t) * 4;
    *(float4*)(Lsum + i) = make_float4(0.f, 0.f, 0.f, 0.f);
  } else {  // bias, 4/thread
    const int i = ((b - PB_BIAS) * 256 + t) * 4;
#pragma unroll
    for (int c = 0; c < 4; c++) {
      const int k = i + c;
      if (k < 3072)
        ball[k] = (k < 1024) ? bq[k] * 0.03125f
                             : ((k < 2048) ? bk[k - 1024] : bv[k - 2048]);
    }
  }
}

// ---------------------------------------------------------------------------
// bf16 transpose: Vt[n][m] = V[m][n]  (V = Call's V columns)
// ---------------------------------------------------------------------------
__global__ void transpose_bf16(const unsigned short* __restrict__ V, int ldv,
                               unsigned short* __restrict__ Vt, int ldvt) {
  __shared__ unsigned short tile[32][33];
  int bx = blockIdx.x * 32;  // n
  int by = blockIdx.y * 32;  // m
  int tx = threadIdx.x, ty = threadIdx.y;
  for (int r = ty; r < 32; r += 8)
    tile[r][tx] = V[(size_t)(by + r) * ldv + bx + tx];
  __syncthreads();
  for (int r = ty; r < 32; r += 8)
    Vt[(size_t)(bx + r) * ldvt + by + tx] = tile[tx][r];
}

// ---------------------------------------------------------------------------
// A·B^T MFMA GEMM: 128x128 tile, 4 waves, BK=64, global_load_lds(16B).
//  * T3-minimum prefetch: double-buffered LDS (2x16KB each of A,B), next
//    tile's 8 gll16 issued BEFORE computing current, raw s_barrier +
//    counted s_waitcnt vmcnt(8) (vmcnt(0) only on the last tile).
//  * T2-style swizzle: read kof ^= (lane&7)<<3 kills the 16-way bank
//    conflict (row stride 128B). gll16 dest stays linear, so the *global*
//    source chunk is pre-permuted: g8 = ((lane&7) ^ (lane>>3)) << 3
//    (rule #21: same involution on source-permute and read side).
//  * Hardening: sched_barrier(0) right after the resident-barrier pins the
//    LDS fragment reads after it (s_barrier is IntrNoMem at IR level —
//    rule #18's hoist hazard); read-release barrier is asm with "memory".
// EPI 0: concat QKV projection. bf16 store, acc*colscale + ball[gc].
// EPI 2: S-phase. U = exp(score) causal (col>row -> 0), bf16 store, skip
//        bn>bm; row sums of U block-reduced then atomicAdd into Lsum.
// EPI 3: O = (U V)/L[row]. split-K over blockIdx.z (1024-wide chunks clipped
//        to Keff=(bm+1)*128); direct store if single chunk else atomicAdd.
// ---------------------------------------------------------------------------
#define BK 64
#define TSZ (128 * 64)

template <int EPI>
__global__ void gemm_tn(const unsigned short* __restrict__ A,
                        const unsigned short* __restrict__ B,
                        void* __restrict__ Cout,
                        const float* __restrict__ bias,
                        float* __restrict__ Lsum,
                        int K, int lda, int ldb, int ldc) {
  int bm, bn, kbeg, kend;
  bool single = true;
  if (EPI == 3) {
    bn = blockIdx.x; bm = blockIdx.y;
    const int Keff = (bm + 1) * 128;
    kbeg = blockIdx.z * 1024;
    if (kbeg >= Keff) return;
    kend = min(kbeg + 1024, Keff);
    single = (Keff <= 1024);
  } else {
    bm = blockIdx.y; bn = blockIdx.x;
    if (EPI == 2 && bn > bm) return;
    kbeg = 0; kend = K;
  }

  __shared__ __align__(16) unsigned short smA[2 * TSZ];
  __shared__ __align__(16) unsigned short smB[2 * TSZ];

  const int t = threadIdx.x;
  const int lane = t & 63, w = t >> 6;
  const int wm = (w & 1) * 64, wn = (w >> 1) * 64;

  f32x4 acc[4][4] = {};

  const unsigned short* Ab = A + (size_t)bm * 128 * lda;
  const unsigned short* Bb = B + (size_t)bn * 128 * ldb;

  const int rA = wm + (lane & 15);
  const int rB = wn + (lane & 15);
  const int kquad = (lane >> 4) << 3;
  const int swz = (lane & 7) << 3;  // read-side XOR (shorts)

  // staging source: row lr = lane>>3; col chunk pre-swizzled so that the
  // linear gll16 write lands data where the swizzled read expects it.
  const int lr = lane >> 3;
  const int g8 = (((lane & 7) ^ lr) << 3);
  const unsigned short* pa = Ab + (size_t)lr * lda + g8 + kbeg;
  const unsigned short* pb = Bb + (size_t)lr * ldb + g8 + kbeg;

  const int nt = (kend - kbeg) / BK;

  auto stage = [&](int c, int tt) {
    const unsigned short* qa = pa + (size_t)tt * BK;
    const unsigned short* qb = pb + (size_t)tt * BK;
    unsigned short* da = smA + c * TSZ;
    unsigned short* db = smB + c * TSZ;
#pragma unroll
    for (int m = 0; m < 4; m++) {
      const int r0 = (w << 5) + (m << 3);  // wave-uniform LDS row base
      gll16(qa + (size_t)r0 * lda, da + r0 * 64);
      gll16(qb + (size_t)r0 * ldb, db + r0 * 64);
    }
  };

  stage(0, 0);  // prologue: 8 loads in flight
  int cur = 0;
  for (int it = 0; it < nt; ++it) {
    if (it + 1 < nt) {
      stage(cur ^ 1, it + 1);  // +8 loads -> 16 outstanding
      // wait for the 8 OLDEST (current tile); next tile stays in flight
      asm volatile("s_waitcnt vmcnt(8)" ::: "memory");
    } else {
      asm volatile("s_waitcnt vmcnt(0)" ::: "memory");
    }
    __builtin_amdgcn_s_barrier();       // all waves' current tile resident
    __builtin_amdgcn_sched_barrier(0);  // pin LDS reads after the barrier

    const unsigned short* sa = smA + cur * TSZ;
    const unsigned short* sb = smB + cur * TSZ;
#pragma unroll
    for (int kk = 0; kk < BK; kk += 32) {
      bf16x8 af[4], bfr[4];
      const int kof = (kk + kquad) ^ swz;  // swizzled slot (2-way max)
#pragma unroll
      for (int i = 0; i < 4; i++)
        af[i] = *(const bf16x8*)(&sa[(rA + i * 16) * 64 + kof]);
#pragma unroll
      for (int j = 0; j < 4; j++)
        bfr[j] = *(const bf16x8*)(&sb[(rB + j * 16) * 64 + kof]);
#pragma unroll
      for (int i = 0; i < 4; i++)
#pragma unroll
        for (int j = 0; j < 4; j++)
          acc[i][j] = __builtin_amdgcn_mfma_f32_16x16x32_bf16(af[i], bfr[j],
                                                              acc[i][j], 0, 0, 0);
    }
    // read-release barrier: all waves done reading buf[cur] before restage.
    asm volatile("s_waitcnt lgkmcnt(0)\ns_barrier" ::: "memory");
    cur ^= 1;
  }

  // Epilogues. C/D layout: col = lane&15, row = (lane>>4)*4 + reg.
  float* Cf = (float*)Cout;
  unsigned short* Ch = (unsigned short*)Cout;
  const int colbase = bn * 128 + wn + (lane & 15);
  const int rowbase = bm * 128 + wm + ((lane >> 4) << 2);

  if (EPI == 0) {
#pragma unroll
    for (int i = 0; i < 4; i++)
#pragma unroll
      for (int j = 0; j < 4; j++) {
        const int gc = colbase + j * 16;
        const float cs = (gc < 1024) ? 0.03125f : 1.0f;
#pragma unroll
        for (int r = 0; r < 4; r++) {
          const int gr = rowbase + i * 16 + r;
          Ch[(size_t)gr * ldc + gc] = f2bf(acc[i][j][r] * cs + bias[gc]);
        }
      }
  } else if (EPI == 2) {
    // U = exp(score), causal; block row-sum -> atomicAdd into Lsum.
    __syncthreads();                 // all LDS reads done; repurpose smA
    float* Lp = (float*)smA;         // 128 floats
    if (t < 128) Lp[t] = 0.f;
    __syncthreads();
#pragma unroll
    for (int i = 0; i < 4; i++)
#pragma unroll
      for (int r = 0; r < 4; r++) {
        const int gr = rowbase + i * 16 + r;
        float sj = 0.f;
#pragma unroll
        for (int j = 0; j < 4; j++) {
          const int gc = colbase + j * 16;
          unsigned short h = 0;
          if (gc <= gr) h = f2bf(__expf(acc[i][j][r]));
          Ch[(size_t)gr * ldc + gc] = h;
          sj += bf2f(h);  // sum the rounded value so L matches stored U
        }
        sj += __shfl_xor(sj, 1);
        sj += __shfl_xor(sj, 2);
        sj += __shfl_xor(sj, 4);
        sj += __shfl_xor(sj, 8);
        if ((lane & 15) == 0)
          atomicAdd(&Lp[wm + ((lane >> 4) << 2) + i * 16 + r], sj);
      }
    __syncthreads();
    if (t < 128) atomicAdd(&Lsum[bm * 128 + t], Lp[t]);
  } else {
#pragma unroll
    for (int i = 0; i < 4; i++)
#pragma unroll
      for (int r = 0; r < 4; r++) {
        const int gr = rowbase + i * 16 + r;
        const float linv = 1.0f / Lsum[gr];
#pragma unroll
        for (int j = 0; j < 4; j++) {
          const int gc = colbase + j * 16;
          const float v = acc[i][j][r] * linv;
          if (single)
            Cf[(size_t)gr * ldc + gc] = v;
          else
            atomicAdd(&Cf[(size_t)gr * ldc + gc], v);
        }
      }
  }
}

// ---------------------------------------------------------------------------
// kernel_launch — 5 launches total.  ws layout (ushort elems):
//   [0,4M)    xb [4096x1024]; after concat GEMM, reused as V^T [1024x4096]
//   [4M,7M)   W_all^T = Wq^T | Wk^T | Wv^T  (3072 x 1024)
//   [7M,19M)  Call [4096x3072] = Q | K | V  (Q pre-scaled by 1/32)
//   [19M,35M) Sb [4096x4096]  (U = exp scores)
//   [35M,..)  ball [3072] f32, Lsum [4096] f32
// ---------------------------------------------------------------------------
extern "C" void kernel_launch(void* const* d_in, const int* in_sizes, int n_in,
                              void* d_out, int out_size, void* d_ws,
                              size_t ws_size, hipStream_t stream) {
  (void)in_sizes; (void)n_in; (void)out_size; (void)ws_size;
  const float* x  = (const float*)d_in[0];
  const float* Wq = (const float*)d_in[1];
  const float* bq = (const float*)d_in[2];
  const float* Wk = (const float*)d_in[3];
  const float* bk = (const float*)d_in[4];
  const float* Wv = (const float*)d_in[5];
  const float* bv = (const float*)d_in[6];
  float* out = (float*)d_out;

  const size_t M1 = (size_t)1024 * 1024;
  unsigned short* xb   = (unsigned short*)d_ws;   // 4M elems; later V^T
  unsigned short* Wt   = xb + 4 * M1;             // 3M elems
  unsigned short* Call = Wt + 3 * M1;             // 12M elems
  unsigned short* Sb   = Call + 12 * M1;          // 16M elems
  float* ball          = (float*)(Sb + 16 * M1);  // 3072 f32
  float* Lsum          = ball + 3072;             // 4096 f32

  // 1) all prep in one launch
  prep<<<PB_TOTAL, 256, 0, stream>>>(x, Wq, Wk, Wv, bq, bk, bv, xb, Wt, out,
                                     ball, Lsum);
  // 2) Call = x @ [Wq|Wk|Wv] + ball. 768 blocks.
  gemm_tn<0><<<dim3(24, 32), 256, 0, stream>>>(xb, Wt, Call, ball, nullptr,
                                               DIM, DIM, DIM, 3 * DIM);
  // 3) V^T into the dead xb slot.
  transpose_bf16<<<dim3(32, 128), dim3(32, 8), 0, stream>>>(Call + 2048,
                                                            3 * DIM, xb, N_TOK);
  // 4) U = exp(Q K^T) causal + row sums Lsum.
  gemm_tn<2><<<dim3(32, 32), 256, 0, stream>>>(Call, Call + 1024, Sb, nullptr,
                                               Lsum, DIM, 3 * DIM, 3 * DIM,
                                               N_TOK);
  // 5) O = (U V) / L, split-K over z (4 chunks of 1024).
  gemm_tn<3><<<dim3(8, 32, 4), 256, 0, stream>>>(Sb, xb, out, nullptr, Lsum,
                                                 N_TOK, N_TOK, N_TOK, DIM);
}

// Round 3
// 227.324 us; speedup vs baseline: 1.0493x; 1.0493x over previous
//
#include <hip/hip_runtime.h>

#define N_TOK 4096
#define DIM   1024

typedef __bf16 bf16x8 __attribute__((ext_vector_type(8)));
typedef float  f32x4  __attribute__((ext_vector_type(4)));

__device__ __forceinline__ unsigned short f2bf(float f) {
  union { float f; unsigned u; } v; v.f = f;
  unsigned u = v.u;
  return (unsigned short)((u + 0x7fffu + ((u >> 16) & 1u)) >> 16);
}
__device__ __forceinline__ float bf2f(unsigned short h) {
  union { unsigned u; float f; } v; v.u = ((unsigned)h) << 16;
  return v.f;
}

// async global->LDS, 16 B/lane: lane's data lands at (uniform lds base) + lane*16
__device__ __forceinline__ void gll16(const unsigned short* g,
                                      unsigned short* l) {
  __builtin_amdgcn_global_load_lds(
      (const __attribute__((address_space(1))) unsigned int*)g,
      (__attribute__((address_space(3))) unsigned int*)l, 16, 0, 0);
}

// ---------------------------------------------------------------------------
// prep kernel — unchanged (proven).
// ---------------------------------------------------------------------------
#define PB_CVT 0
#define PB_TQ 2048
#define PB_ZERO 5120
#define PB_LSUM 5888
#define PB_BIAS 5892
#define PB_TOTAL 5895

__global__ void prep(const float* __restrict__ x, const float* __restrict__ Wq,
                     const float* __restrict__ Wk, const float* __restrict__ Wv,
                     const float* __restrict__ bq, const float* __restrict__ bk,
                     const float* __restrict__ bv,
                     unsigned short* __restrict__ xb,
                     unsigned short* __restrict__ Wt,
                     float* __restrict__ out, float* __restrict__ ball,
                     float* __restrict__ Lsum) {
  const int b = blockIdx.x;
  const int t = threadIdx.x;
  if (b < PB_TQ) {  // CVT
    const int i = ((b - PB_CVT) * 256 + t) * 8;
    float4 v0 = *(const float4*)(x + i);
    float4 v1 = *(const float4*)(x + i + 4);
    ushort4 r0, r1;
    r0.x = f2bf(v0.x); r0.y = f2bf(v0.y); r0.z = f2bf(v0.z); r0.w = f2bf(v0.w);
    r1.x = f2bf(v1.x); r1.y = f2bf(v1.y); r1.z = f2bf(v1.z); r1.w = f2bf(v1.w);
    *(ushort4*)(xb + i) = r0;
    *(ushort4*)(xb + i + 4) = r1;
  } else if (b < PB_ZERO) {  // transpose one 32x32 tile of one W
    const int which = (b - PB_TQ) >> 10;          // 0,1,2
    const int lb = (b - PB_TQ) & 1023;
    const float* W = (which == 0) ? Wq : (which == 1) ? Wk : Wv;
    unsigned short* D = Wt + (size_t)which * 1024 * 1024;
    __shared__ float tile[32][33];
    const int bx = (lb & 31) * 32, by = (lb >> 5) * 32;
    const int tx = t & 31, ty = t >> 5;  // ty in 0..7
    for (int r = ty; r < 32; r += 8)
      tile[r][tx] = W[(size_t)(by + r) * DIM + bx + tx];
    __syncthreads();
    for (int r = ty; r < 32; r += 8)
      D[(size_t)(bx + r) * DIM + by + tx] = f2bf(tile[tx][r]);
  } else if (b < PB_LSUM) {  // zero out rows >= 1024 (3M floats)
    float4* p = (float4*)(out + (size_t)1024 * DIM);
    const int i = ((b - PB_ZERO) * 256 + t) * 4;
#pragma unroll
    for (int c = 0; c < 4; c++) p[i + c] = make_float4(0.f, 0.f, 0.f, 0.f);
  } else if (b < PB_BIAS) {  // Lsum zero
    const int i = ((b - PB_LSUM) * 256 + t) * 4;
    *(float4*)(Lsum + i) = make_float4(0.f, 0.f, 0.f, 0.f);
  } else {  // bias, 4/thread
    const int i = ((b - PB_BIAS) * 256 + t) * 4;
#pragma unroll
    for (int c = 0; c < 4; c++) {
      const int k = i + c;
      if (k < 3072)
        ball[k] = (k < 1024) ? bq[k] * 0.03125f
                             : ((k < 2048) ? bk[k - 1024] : bv[k - 2048]);
    }
  }
}

// ---------------------------------------------------------------------------
// bf16 transpose: Vt[n][m] = V[m][n]  — unchanged.
// ---------------------------------------------------------------------------
__global__ void transpose_bf16(const unsigned short* __restrict__ V, int ldv,
                               unsigned short* __restrict__ Vt, int ldvt) {
  __shared__ unsigned short tile[32][33];
  int bx = blockIdx.x * 32;  // n
  int by = blockIdx.y * 32;  // m
  int tx = threadIdx.x, ty = threadIdx.y;
  for (int r = ty; r < 32; r += 8)
    tile[r][tx] = V[(size_t)(by + r) * ldv + bx + tx];
  __syncthreads();
  for (int r = ty; r < 32; r += 8)
    Vt[(size_t)(bx + r) * ldvt + by + tx] = tile[tx][r];
}

// ---------------------------------------------------------------------------
// 256x256 8-phase A·B^T GEMM (m201 template, plain-HIP port).
//   8 waves (512 thr) as 2(M) x 4(N); per-wave output 128x64 = acc[8][4].
//   BK=64, LDS 128KB = 2 dbuf x (A 256x64 + B 256x64) bf16.
//   K-tile = 4 phases; each phase: {ds_read subtile | issue stage} ->
//   s_barrier -> lgkmcnt(0) -> setprio(1) 16 MFMA setprio(0) -> s_barrier.
//   Next tile's 8 gll16 issued at phases 0-1; single vmcnt(0) sits at the
//   END of the tile (loads are then 2-3 phases old ≈ >1000cy — exposes
//   only queue tail, unlike round-0's issue-then-drain).
//   T2 swizzle: proven involution — linear gll16 dest, source chunk
//   pre-XOR'd by (row&7), read offset kof ^ ((lane&7)<<3).
//   T1: bijective XCD swizzle (m204) on the 2D grid.
// EPI 0: QKV projection (bias+scale, bf16).  EPI 2: U=exp(score) causal +
// row-sum->Lsum.  EPI 3: O=(U V)/L, split-K over z, atomicAdd when multi.
// ---------------------------------------------------------------------------
#define BK 64

template <int EPI>
__global__ __launch_bounds__(512, 2) void gemm_tn(
    const unsigned short* __restrict__ A, const unsigned short* __restrict__ B,
    void* __restrict__ Cout, const float* __restrict__ bias,
    float* __restrict__ Lsum, int K, int lda, int ldb, int ldc) {
  // ---- bijective XCD swizzle on the (x,y) grid (m204) ----
  const int nwg = gridDim.x * gridDim.y;
  const int orig = blockIdx.y * gridDim.x + blockIdx.x;
  const int q8 = nwg >> 3, r8 = nwg & 7;
  const int xcd = orig & 7;
  const int wg = ((xcd < r8) ? xcd * (q8 + 1) : r8 * (q8 + 1) + (xcd - r8) * q8)
                 + (orig >> 3);
  int bm = wg / gridDim.x;
  int bn = wg % gridDim.x;

  int kbeg, kend;
  bool single = true;
  if (EPI == 3) {
    const int Keff = (bm + 1) * 256;
    kbeg = blockIdx.z * 1024;
    if (kbeg >= Keff) return;
    kend = min(kbeg + 1024, Keff);
    single = (Keff <= 1024);
  } else {
    if (EPI == 2 && bn > bm) return;
    kbeg = 0; kend = K;
  }

  __shared__ __align__(16) unsigned short smA[2][256 * 64];  // 64 KB
  __shared__ __align__(16) unsigned short smB[2][256 * 64];  // 64 KB

  const int t = threadIdx.x;
  const int lane = t & 63, w = t >> 6;   // 8 waves
  const int wr = w >> 2;                  // 0..1 : M half (128 rows)
  const int wc = w & 3;                   // 0..3 : N quarter (64 cols)
  const int lane15 = lane & 15;
  const int kq = (lane >> 4) << 3;        // frag k sub-offset
  const int swz = (lane & 7) << 3;        // read-side XOR (shorts)

  f32x4 acc[8][4] = {};

  // staging source: row lr = lane>>3 within an 8-row call; column chunk
  // pre-XOR'd so the linear gll16 write matches the swizzled read.
  const int lr = lane >> 3;
  const int g8 = ((lane & 7) ^ lr) << 3;
  const unsigned short* srcA =
      A + (size_t)((size_t)bm * 256 + (w << 4) + lr) * lda + g8 + kbeg;
  const unsigned short* srcB =
      B + (size_t)((size_t)bn * 256 + (w << 4) + lr) * ldb + g8 + kbeg;

  const int nt = (kend - kbeg) / BK;

  // stage one "pair" (A-half + B-half, rows half*128..+127): 4 gll16/wave
  auto stg = [&](int bufi, int tt, int half) {
#pragma unroll
    for (int c = 0; c < 2; c++) {
      const int rb = half * 128 + (w << 4) + (c << 3);  // wave-uniform
      const size_t go = (size_t)(half * 128 + (c << 3));
      gll16(srcA + go * lda + (size_t)tt * BK, &smA[bufi][rb * 64]);
      gll16(srcB + go * ldb + (size_t)tt * BK, &smB[bufi][rb * 64]);
    }
  };

  // prologue: tile 0 fully staged
  stg(0, 0, 0);
  stg(0, 0, 1);
  asm volatile("s_waitcnt vmcnt(0)" ::: "memory");
  __builtin_amdgcn_s_barrier();

  int buf = 0;
  for (int tt = 0; tt < nt; ++tt) {
    const int nx = tt + 1;
    const unsigned short* sA = smA[buf];
    const unsigned short* sB = smB[buf];
    bf16x8 bA[4], bB0[4], bB1[4];
    const int kof0 = kq ^ swz;          // kk=0 half
    const int kof1 = (32 + kq) ^ swz;   // kk=32 half

    // ---- phase 0: (h=0, q=0) ----
#pragma unroll
    for (int i = 0; i < 4; i++)
      bA[i] = *(const bf16x8*)&sA[(wr * 128 + i * 16 + lane15) * 64 + kof0];
#pragma unroll
    for (int j = 0; j < 4; j++)
      bB0[j] = *(const bf16x8*)&sB[(wc * 64 + j * 16 + lane15) * 64 + kof0];
    if (nx < nt) stg(buf ^ 1, nx, 0);
    __builtin_amdgcn_s_barrier();
    asm volatile("s_waitcnt lgkmcnt(0)" ::: "memory");
    __builtin_amdgcn_s_setprio(1);
#pragma unroll
    for (int i = 0; i < 4; i++)
#pragma unroll
      for (int j = 0; j < 4; j++)
        acc[i][j] = __builtin_amdgcn_mfma_f32_16x16x32_bf16(bA[i], bB0[j],
                                                            acc[i][j], 0, 0, 0);
    __builtin_amdgcn_s_setprio(0);
    __builtin_amdgcn_s_barrier();

    // ---- phase 1: (h=0, q=1) ----
#pragma unroll
    for (int i = 0; i < 4; i++)
      bA[i] = *(const bf16x8*)&sA[(wr * 128 + i * 16 + lane15) * 64 + kof1];
#pragma unroll
    for (int j = 0; j < 4; j++)
      bB1[j] = *(const bf16x8*)&sB[(wc * 64 + j * 16 + lane15) * 64 + kof1];
    if (nx < nt) stg(buf ^ 1, nx, 1);
    __builtin_amdgcn_s_barrier();
    asm volatile("s_waitcnt lgkmcnt(0)" ::: "memory");
    __builtin_amdgcn_s_setprio(1);
#pragma unroll
    for (int i = 0; i < 4; i++)
#pragma unroll
      for (int j = 0; j < 4; j++)
        acc[i][j] = __builtin_amdgcn_mfma_f32_16x16x32_bf16(bA[i], bB1[j],
                                                            acc[i][j], 0, 0, 0);
    __builtin_amdgcn_s_setprio(0);
    __builtin_amdgcn_s_barrier();

    // ---- phase 2: (h=1, q=0) ----
#pragma unroll
    for (int i = 0; i < 4; i++)
      bA[i] = *(const bf16x8*)&sA[(wr * 128 + 64 + i * 16 + lane15) * 64 + kof0];
    __builtin_amdgcn_s_barrier();
    asm volatile("s_waitcnt lgkmcnt(0)" ::: "memory");
    __builtin_amdgcn_s_setprio(1);
#pragma unroll
    for (int i = 0; i < 4; i++)
#pragma unroll
      for (int j = 0; j < 4; j++)
        acc[4 + i][j] = __builtin_amdgcn_mfma_f32_16x16x32_bf16(
            bA[i], bB0[j], acc[4 + i][j], 0, 0, 0);
    __builtin_amdgcn_s_setprio(0);
    __builtin_amdgcn_s_barrier();

    // ---- phase 3: (h=1, q=1) ----
#pragma unroll
    for (int i = 0; i < 4; i++)
      bA[i] = *(const bf16x8*)&sA[(wr * 128 + 64 + i * 16 + lane15) * 64 + kof1];
    __builtin_amdgcn_s_barrier();
    asm volatile("s_waitcnt lgkmcnt(0)" ::: "memory");
    __builtin_amdgcn_s_setprio(1);
#pragma unroll
    for (int i = 0; i < 4; i++)
#pragma unroll
      for (int j = 0; j < 4; j++)
        acc[4 + i][j] = __builtin_amdgcn_mfma_f32_16x16x32_bf16(
            bA[i], bB1[j], acc[4 + i][j], 0, 0, 0);
    __builtin_amdgcn_s_setprio(0);
    // next tile resident before any wave proceeds (loads are 2-3 phases old)
    if (nx < nt) asm volatile("s_waitcnt vmcnt(0)" ::: "memory");
    __builtin_amdgcn_s_barrier();
    buf ^= 1;
  }

  // Epilogues. C/D frag layout: col = lane&15, row = (lane>>4)*4 + reg.
  float* Cf = (float*)Cout;
  unsigned short* Ch = (unsigned short*)Cout;
  const int colbase = bn * 256 + wc * 64 + lane15;
  const int rowbase = bm * 256 + wr * 128 + ((lane >> 4) << 2);

  if (EPI == 0) {
#pragma unroll
    for (int i = 0; i < 8; i++)
#pragma unroll
      for (int j = 0; j < 4; j++) {
        const int gc = colbase + j * 16;
        const float cs = (gc < 1024) ? 0.03125f : 1.0f;
        const float bs = bias[gc];
#pragma unroll
        for (int r = 0; r < 4; r++) {
          const int gr = rowbase + i * 16 + r;
          Ch[(size_t)gr * ldc + gc] = f2bf(acc[i][j][r] * cs + bs);
        }
      }
  } else if (EPI == 2) {
    __syncthreads();                 // all LDS reads done; repurpose smA
    float* Lp = (float*)smA;         // 256 floats
    if (t < 256) Lp[t] = 0.f;
    __syncthreads();
#pragma unroll
    for (int i = 0; i < 8; i++)
#pragma unroll
      for (int r = 0; r < 4; r++) {
        const int gr = rowbase + i * 16 + r;
        float sj = 0.f;
#pragma unroll
        for (int j = 0; j < 4; j++) {
          const int gc = colbase + j * 16;
          unsigned short h = 0;
          if (gc <= gr) h = f2bf(__expf(acc[i][j][r]));
          Ch[(size_t)gr * ldc + gc] = h;
          sj += bf2f(h);  // sum rounded value so L matches stored U
        }
        sj += __shfl_xor(sj, 1);
        sj += __shfl_xor(sj, 2);
        sj += __shfl_xor(sj, 4);
        sj += __shfl_xor(sj, 8);
        if (lane15 == 0)
          atomicAdd(&Lp[wr * 128 + i * 16 + ((lane >> 4) << 2) + r], sj);
      }
    __syncthreads();
    if (t < 256) atomicAdd(&Lsum[bm * 256 + t], Lp[t]);
  } else {
#pragma unroll
    for (int i = 0; i < 8; i++)
#pragma unroll
      for (int r = 0; r < 4; r++) {
        const int gr = rowbase + i * 16 + r;
        const float linv = 1.0f / Lsum[gr];
#pragma unroll
        for (int j = 0; j < 4; j++) {
          const int gc = colbase + j * 16;
          const float v = acc[i][j][r] * linv;
          if (single)
            Cf[(size_t)gr * ldc + gc] = v;
          else
            atomicAdd(&Cf[(size_t)gr * ldc + gc], v);
        }
      }
  }
}

// ---------------------------------------------------------------------------
// kernel_launch — 5 launches.  ws layout (ushort elems):
//   [0,4M)    xb [4096x1024]; after concat GEMM, reused as V^T [1024x4096]
//   [4M,7M)   W_all^T = Wq^T | Wk^T | Wv^T  (3072 x 1024)
//   [7M,19M)  Call [4096x3072] = Q | K | V  (Q pre-scaled by 1/32)
//   [19M,35M) Sb [4096x4096]  (U = exp scores)
//   [35M,..)  ball [3072] f32, Lsum [4096] f32
// ---------------------------------------------------------------------------
extern "C" void kernel_launch(void* const* d_in, const int* in_sizes, int n_in,
                              void* d_out, int out_size, void* d_ws,
                              size_t ws_size, hipStream_t stream) {
  (void)in_sizes; (void)n_in; (void)out_size; (void)ws_size;
  const float* x  = (const float*)d_in[0];
  const float* Wq = (const float*)d_in[1];
  const float* bq = (const float*)d_in[2];
  const float* Wk = (const float*)d_in[3];
  const float* bk = (const float*)d_in[4];
  const float* Wv = (const float*)d_in[5];
  const float* bv = (const float*)d_in[6];
  float* out = (float*)d_out;

  const size_t M1 = (size_t)1024 * 1024;
  unsigned short* xb   = (unsigned short*)d_ws;   // 4M elems; later V^T
  unsigned short* Wt   = xb + 4 * M1;             // 3M elems
  unsigned short* Call = Wt + 3 * M1;             // 12M elems
  unsigned short* Sb   = Call + 12 * M1;          // 16M elems
  float* ball          = (float*)(Sb + 16 * M1);  // 3072 f32
  float* Lsum          = ball + 3072;             // 4096 f32

  // 1) all prep in one launch
  prep<<<PB_TOTAL, 256, 0, stream>>>(x, Wq, Wk, Wv, bq, bk, bv, xb, Wt, out,
                                     ball, Lsum);
  // 2) Call = x @ [Wq|Wk|Wv] + ball. 256² tiles: grid (3072/256, 4096/256).
  gemm_tn<0><<<dim3(12, 16), 512, 0, stream>>>(xb, Wt, Call, ball, nullptr,
                                               DIM, DIM, DIM, 3 * DIM);
  // 3) V^T into the dead xb slot.
  transpose_bf16<<<dim3(32, 128), dim3(32, 8), 0, stream>>>(Call + 2048,
                                                            3 * DIM, xb, N_TOK);
  // 4) U = exp(Q K^T) causal + row sums Lsum. 256² tiles, tri.
  gemm_tn<2><<<dim3(16, 16), 512, 0, stream>>>(Call, Call + 1024, Sb, nullptr,
                                               Lsum, DIM, 3 * DIM, 3 * DIM,
                                               N_TOK);
  // 5) O = (U V) / L, split-K over z (4 chunks of 1024).
  gemm_tn<3><<<dim3(4, 16, 4), 512, 0, stream>>>(Sb, xb, out, nullptr, Lsum,
                                                 N_TOK, N_TOK, N_TOK, DIM);
}